// Round 1
// baseline (155.648 us; speedup 1.0000x reference)
//
#include <hip/hip_runtime.h>
#include <math.h>

#define BH 256
#define BW 256
#define NB 32
#define NC 32
#define RB 64   // reduction blocks per batch

// ---------------- Kernel 1: per-batch weighted sum  S[b] = sum x[b,h,w,c]*Wm[c]
__global__ __launch_bounds__(256) void k_reduce(const float* __restrict__ x,
                                                const float* __restrict__ Wm,
                                                float* __restrict__ partial) {
    const int b   = blockIdx.y;
    const int blk = blockIdx.x;
    const int tid = blk * 256 + threadIdx.x;            // 0..16383 within batch
    const int threads_per_batch = RB * 256;             // 16384
    // grid stride in elements = 16384*4 = 65536, divisible by NC=32 ->
    // channel base is loop-invariant per thread.
    const int cb = (tid * 4) & (NC - 1);
    const float w0 = Wm[cb + 0], w1 = Wm[cb + 1], w2 = Wm[cb + 2], w3 = Wm[cb + 3];

    const float4* xb = (const float4*)(x + (size_t)b * BH * BW * NC);
    const int n4 = BH * BW * NC / 4;                    // 524288
    float s = 0.f;
    for (int i = tid; i < n4; i += threads_per_batch) {
        float4 v = xb[i];
        s += v.x * w0 + v.y * w1 + v.z * w2 + v.w * w3;
    }
    // wave reduce (wave = 64)
    for (int off = 32; off; off >>= 1) s += __shfl_down(s, off, 64);
    __shared__ float red[4];
    const int lane = threadIdx.x & 63, wv = threadIdx.x >> 6;
    if (lane == 0) red[wv] = s;
    __syncthreads();
    if (threadIdx.x == 0)
        partial[b * RB + blk] = red[0] + red[1] + red[2] + red[3];
}

// ---------------- Kernel 2: finish reduction, compute per-batch rotation params
__global__ void k_angle(const float* __restrict__ partial,
                        const float* __restrict__ bias,
                        float4* __restrict__ params) {
    const int b = threadIdx.x;
    if (b >= NB) return;
    float s = 0.f;
    for (int i = 0; i < RB; ++i) s += partial[b * RB + i];
    const float pi = 3.14159265358979323846f;
    float angle = tanhf(s * (1.f / (BH * BW)) + bias[0]) * pi;
    angle = fminf(fmaxf(angle, -pi), pi);
    const float cc = cosf(angle), ss = sinf(angle);
    const float w1 = (float)(BW - 1), h1 = (float)(BH - 1);
    const float xoff = (w1 - (cc * w1 - ss * h1)) * 0.5f;
    const float yoff = (h1 - (ss * w1 + cc * h1)) * 0.5f;
    params[b] = make_float4(cc, ss, xoff, yoff);
}

// ---------------- Kernel 3: bilinear rotate, one thread per (pixel, 4 channels)
__global__ __launch_bounds__(256) void k_rotate(const float* __restrict__ x,
                                                const float4* __restrict__ params,
                                                float* __restrict__ out) {
    const int gid = blockIdx.x * 256 + threadIdx.x;     // 0 .. 16,777,215
    const int c4  = (gid & 7) * 4;                      // channel base
    const int pid = gid >> 3;                           // pixel id
    const int b   = pid >> 16;
    const int p   = pid & 65535;
    const int yo  = p >> 8;
    const int xo  = p & 255;

    const float4 prm = params[b];
    const float cc = prm.x, ss = prm.y, xoff = prm.z, yoff = prm.w;
    const float fx = (float)xo, fy = (float)yo;
    const float in_x = cc * fx - ss * fy + xoff;
    const float in_y = ss * fx + cc * fy + yoff;
    const float x0 = floorf(in_x), y0 = floorf(in_y);
    const float wx = in_x - x0, wy = in_y - y0;
    const int x0i = (int)x0, y0i = (int)y0;

    const float* xb = x + (size_t)b * (BH * BW * NC);

    auto pix = [&](int yi, int xi) -> float4 {
        const bool valid = (xi >= 0) & (xi < BW) & (yi >= 0) & (yi < BH);
        const int yc = min(max(yi, 0), BH - 1);
        const int xc = min(max(xi, 0), BW - 1);
        float4 v = *(const float4*)(xb + ((size_t)yc * BW + xc) * NC + c4);
        const float f = valid ? 1.f : 0.f;
        v.x *= f; v.y *= f; v.z *= f; v.w *= f;
        return v;
    };

    const float4 v00 = pix(y0i, x0i);
    const float4 v01 = pix(y0i, x0i + 1);
    const float4 v10 = pix(y0i + 1, x0i);
    const float4 v11 = pix(y0i + 1, x0i + 1);

    const float owx = 1.f - wx, owy = 1.f - wy;
    float4 r;
    r.x = (v00.x * owx + v01.x * wx) * owy + (v10.x * owx + v11.x * wx) * wy;
    r.y = (v00.y * owx + v01.y * wx) * owy + (v10.y * owx + v11.y * wx) * wy;
    r.z = (v00.z * owx + v01.z * wx) * owy + (v10.z * owx + v11.z * wx) * wy;
    r.w = (v00.w * owx + v01.w * wx) * owy + (v10.w * owx + v11.w * wx) * wy;

    *(float4*)(out + (size_t)gid * 4) = r;
}

extern "C" void kernel_launch(void* const* d_in, const int* in_sizes, int n_in,
                              void* d_out, int out_size, void* d_ws, size_t ws_size,
                              hipStream_t stream) {
    const float* x    = (const float*)d_in[0];
    const float* Wm   = (const float*)d_in[1];
    const float* bias = (const float*)d_in[2];
    float* out = (float*)d_out;

    float*  partial = (float*)d_ws;                         // NB*RB floats = 8 KiB
    float4* params  = (float4*)((char*)d_ws + NB * RB * sizeof(float)); // 16B-aligned

    dim3 g1(RB, NB);
    k_reduce<<<g1, 256, 0, stream>>>(x, Wm, partial);
    k_angle<<<1, 64, 0, stream>>>(partial, bias, params);

    const int total4 = NB * BH * BW * NC / 4;               // 16,777,216
    k_rotate<<<total4 / 256, 256, 0, stream>>>(x, params, out);
}

// Round 3
// 130.833 us; speedup vs baseline: 1.1897x; 1.1897x over previous
//
#include <hip/hip_runtime.h>
#include <math.h>

#define BH 256
#define BW 256
#define NB 32
#define NC 32
#define RB 64   // reduction blocks per batch

typedef float nfloat4 __attribute__((ext_vector_type(4)));  // native vec for nontemporal builtin

// ---------------- Kernel 1: per-batch weighted sum  S[b] = sum x[b,h,w,c]*Wm[c]
__global__ __launch_bounds__(256) void k_reduce(const float* __restrict__ x,
                                                const float* __restrict__ Wm,
                                                float* __restrict__ partial) {
    const int b   = blockIdx.y;
    const int blk = blockIdx.x;
    const int tid = blk * 256 + threadIdx.x;            // 0..16383 within batch
    const int threads_per_batch = RB * 256;             // 16384
    // stride in elements = 16384*4 = 65536, divisible by NC=32 ->
    // channel base is loop-invariant per thread.
    const int cb = (tid * 4) & (NC - 1);
    const float w0 = Wm[cb + 0], w1 = Wm[cb + 1], w2 = Wm[cb + 2], w3 = Wm[cb + 3];

    const float4* xb = (const float4*)(x + (size_t)b * BH * BW * NC);
    const int n4 = BH * BW * NC / 4;                    // 524288
    float s0 = 0.f, s1 = 0.f;
    // 2-deep unroll: 32 iterations total, 2 loads in flight
    for (int i = tid; i < n4; i += 2 * threads_per_batch) {
        float4 v0 = xb[i];
        float4 v1 = xb[i + threads_per_batch];
        s0 += v0.x * w0 + v0.y * w1 + v0.z * w2 + v0.w * w3;
        s1 += v1.x * w0 + v1.y * w1 + v1.z * w2 + v1.w * w3;
    }
    float s = s0 + s1;
    // wave reduce (wave = 64)
    for (int off = 32; off; off >>= 1) s += __shfl_down(s, off, 64);
    __shared__ float red[4];
    const int lane = threadIdx.x & 63, wv = threadIdx.x >> 6;
    if (lane == 0) red[wv] = s;
    __syncthreads();
    if (threadIdx.x == 0)
        partial[b * RB + blk] = red[0] + red[1] + red[2] + red[3];
}

// ---------------- Kernel 2: finish reduction, compute per-batch rotation params
__global__ void k_angle(const float* __restrict__ partial,
                        const float* __restrict__ bias,
                        float4* __restrict__ params) {
    const int b = threadIdx.x;
    if (b >= NB) return;
    float s = 0.f;
    for (int i = 0; i < RB; ++i) s += partial[b * RB + i];
    const float pi = 3.14159265358979323846f;
    float angle = tanhf(s * (1.f / (BH * BW)) + bias[0]) * pi;
    angle = fminf(fmaxf(angle, -pi), pi);
    const float cc = cosf(angle), ss = sinf(angle);
    const float w1 = (float)(BW - 1), h1 = (float)(BH - 1);
    const float xoff = (w1 - (cc * w1 - ss * h1)) * 0.5f;
    const float yoff = (h1 - (ss * w1 + cc * h1)) * 0.5f;
    params[b] = make_float4(cc, ss, xoff, yoff);
}

// ---------------- Kernel 3: bilinear rotate, one thread per (pixel, 4 channels)
// Output stores are NONTEMPORAL so the 256 MB of writes don't evict x from the
// 256 MB Infinity Cache -> gather reads stay L3-resident after k_reduce's pass.
__global__ __launch_bounds__(256) void k_rotate(const float* __restrict__ x,
                                                const float4* __restrict__ params,
                                                float* __restrict__ out) {
    const int gid = blockIdx.x * 256 + threadIdx.x;     // 0 .. 16,777,215
    const int c4  = (gid & 7) * 4;                      // channel base
    const int pid = gid >> 3;                           // pixel id
    const int b   = pid >> 16;
    const int p   = pid & 65535;
    const int yo  = p >> 8;
    const int xo  = p & 255;

    const float4 prm = params[b];
    const float cc = prm.x, ss = prm.y, xoff = prm.z, yoff = prm.w;
    const float fx = (float)xo, fy = (float)yo;
    const float in_x = cc * fx - ss * fy + xoff;
    const float in_y = ss * fx + cc * fy + yoff;
    const float x0 = floorf(in_x), y0 = floorf(in_y);
    const float wx = in_x - x0, wy = in_y - y0;
    const int x0i = (int)x0, y0i = (int)y0;

    const float* xb = x + (size_t)b * (BH * BW * NC);

    auto pix = [&](int yi, int xi) -> float4 {
        const bool valid = (xi >= 0) & (xi < BW) & (yi >= 0) & (yi < BH);
        const int yc = min(max(yi, 0), BH - 1);
        const int xc = min(max(xi, 0), BW - 1);
        float4 v = *(const float4*)(xb + ((size_t)yc * BW + xc) * NC + c4);
        const float f = valid ? 1.f : 0.f;
        v.x *= f; v.y *= f; v.z *= f; v.w *= f;
        return v;
    };

    const float4 v00 = pix(y0i, x0i);
    const float4 v01 = pix(y0i, x0i + 1);
    const float4 v10 = pix(y0i + 1, x0i);
    const float4 v11 = pix(y0i + 1, x0i + 1);

    const float owx = 1.f - wx, owy = 1.f - wy;
    nfloat4 r;
    r.x = (v00.x * owx + v01.x * wx) * owy + (v10.x * owx + v11.x * wx) * wy;
    r.y = (v00.y * owx + v01.y * wx) * owy + (v10.y * owx + v11.y * wx) * wy;
    r.z = (v00.z * owx + v01.z * wx) * owy + (v10.z * owx + v11.z * wx) * wy;
    r.w = (v00.w * owx + v01.w * wx) * owy + (v10.w * owx + v11.w * wx) * wy;

    __builtin_nontemporal_store(r, (nfloat4*)(out + (size_t)gid * 4));
}

extern "C" void kernel_launch(void* const* d_in, const int* in_sizes, int n_in,
                              void* d_out, int out_size, void* d_ws, size_t ws_size,
                              hipStream_t stream) {
    const float* x    = (const float*)d_in[0];
    const float* Wm   = (const float*)d_in[1];
    const float* bias = (const float*)d_in[2];
    float* out = (float*)d_out;

    float*  partial = (float*)d_ws;                         // NB*RB floats = 8 KiB
    float4* params  = (float4*)((char*)d_ws + NB * RB * sizeof(float)); // 16B-aligned

    dim3 g1(RB, NB);
    k_reduce<<<g1, 256, 0, stream>>>(x, Wm, partial);
    k_angle<<<1, 64, 0, stream>>>(partial, bias, params);

    const int total4 = NB * BH * BW * NC / 4;               // 16,777,216
    k_rotate<<<total4 / 256, 256, 0, stream>>>(x, params, out);
}